// Round 2
// baseline (684.023 us; speedup 1.0000x reference)
//
#include <hip/hip_runtime.h>
#include <hip/hip_bf16.h>

#define BB 16
#define NN 64
#define PREVN 6
#define PREDN 30
#define HH 256
#define EE 4032              // NN*(NN-1)
#define EROWS (BB*EE)        // 64512
#define NROWS (BB*NN)        // 1024

// ---- workspace layout (float element offsets) ----
enum : int {
  OFF_STATS_E = 0,       // 1024: [0:256]=sum [256:512]=sumsq [512:768]=a [768:1024]=c
  OFF_STATS_M = 1024,    // 1024
  OFF_X       = 2048,    // 1024*256
  OFF_NODES   = 264192,  // 1024*512
  OFF_M2      = 788480,  // 1024*256
  WS_FLOATS   = 1050624
};
#define E2_BYTE_OFF ((size_t)WS_FLOATS * 4)   // bf16 edge h2: 64512*256*2 B (16B-aligned)

__device__ __forceinline__ float eluf(float v) { return v > 0.f ? v : expm1f(v); }

// ---- zero the stats region (no hipMemsetAsync — keep graph capture trivially safe) ----
__global__ void k_zero(float* __restrict__ p) {
  p[blockIdx.x * 256 + threadIdx.x] = 0.f;
}

// ---- x = rel_pos @ W_traj + b_traj ; one block per (b,n) row ----
__global__ __launch_bounds__(256) void k_x(const float* __restrict__ centers,
                                           const float* __restrict__ Wt,
                                           const float* __restrict__ bt,
                                           float* __restrict__ ws) {
  int row = blockIdx.x, col = threadIdx.x;
  const float* c = centers + row * (PREVN * 2);
  float rp[12];
  #pragma unroll
  for (int t = 0; t < 5; ++t) {
    rp[2 + 2*t] = c[(t+1)*2 + 0] - c[t*2 + 0];
    rp[3 + 2*t] = c[(t+1)*2 + 1] - c[t*2 + 1];
  }
  float acc = bt[col];
  #pragma unroll
  for (int k = 2; k < 12; ++k) acc += rp[k] * Wt[k*HH + col];
  ws[OFF_X + row*HH + col] = acc;
}

// ---- fused 2-layer MLP (pre-BN). MODE 0: edge (gather x, write bf16 e2)
//      MODE 1: node (read nodes, write f32 m2). 16 rows/block, 256 threads,
//      each thread 4 rows x 4 cols. ----
template<int MODE>
__global__ __launch_bounds__(256) void k_mlp(float* __restrict__ ws,
                                             const float* __restrict__ W1,
                                             const float* __restrict__ b1,
                                             const float* __restrict__ W2,
                                             const float* __restrict__ b2,
                                             __hip_bfloat16* __restrict__ e2) {
  __shared__ float in_lds[16][512];
  __shared__ float h1[16][256];
  const int tid = threadIdx.x;
  const int tx = tid & 63, ty = tid >> 6;   // cols 4tx..4tx+3, rows 4ty..4ty+3
  const int row0 = blockIdx.x * 16;

  if (MODE == 0) {
    const float* xin = ws + OFF_X;
    #pragma unroll
    for (int r = 0; r < 16; ++r) {
      int g = row0 + r;
      int b = g / EE; int e = g - b * EE;
      int rc = e / 63; int jj = e - rc * 63;
      int sd = jj + (jj >= rc ? 1 : 0);
      in_lds[r][tid]       = xin[(b*NN + rc)*HH + tid];
      in_lds[r][256 + tid] = xin[(b*NN + sd)*HH + tid];
    }
  } else {
    const float* xin = ws + OFF_NODES;
    #pragma unroll
    for (int r = 0; r < 16; ++r) {
      int g = row0 + r;
      in_lds[r][tid]       = xin[g*512 + tid];
      in_lds[r][256 + tid] = xin[g*512 + 256 + tid];
    }
  }
  __syncthreads();

  float acc[4][4];
  {
    float4 bv = *reinterpret_cast<const float4*>(&b1[4*tx]);
    const float* bvp = reinterpret_cast<const float*>(&bv);
    #pragma unroll
    for (int i = 0; i < 4; ++i)
      #pragma unroll
      for (int j = 0; j < 4; ++j) acc[i][j] = bvp[j];
  }
  for (int k = 0; k < 512; k += 4) {
    float4 w0 = *reinterpret_cast<const float4*>(&W1[(k+0)*HH + 4*tx]);
    float4 w1 = *reinterpret_cast<const float4*>(&W1[(k+1)*HH + 4*tx]);
    float4 w2 = *reinterpret_cast<const float4*>(&W1[(k+2)*HH + 4*tx]);
    float4 w3 = *reinterpret_cast<const float4*>(&W1[(k+3)*HH + 4*tx]);
    const float* w0p = reinterpret_cast<const float*>(&w0);
    const float* w1p = reinterpret_cast<const float*>(&w1);
    const float* w2p = reinterpret_cast<const float*>(&w2);
    const float* w3p = reinterpret_cast<const float*>(&w3);
    #pragma unroll
    for (int i = 0; i < 4; ++i) {
      float4 iv = *reinterpret_cast<const float4*>(&in_lds[4*ty + i][k]);
      #pragma unroll
      for (int j = 0; j < 4; ++j)
        acc[i][j] += iv.x*w0p[j] + iv.y*w1p[j] + iv.z*w2p[j] + iv.w*w3p[j];
    }
  }
  #pragma unroll
  for (int i = 0; i < 4; ++i) {
    float4 hv;
    hv.x = eluf(acc[i][0]); hv.y = eluf(acc[i][1]);
    hv.z = eluf(acc[i][2]); hv.w = eluf(acc[i][3]);
    *reinterpret_cast<float4*>(&h1[4*ty + i][4*tx]) = hv;
  }
  __syncthreads();

  float acc2[4][4];
  {
    float4 bv = *reinterpret_cast<const float4*>(&b2[4*tx]);
    const float* bvp = reinterpret_cast<const float*>(&bv);
    #pragma unroll
    for (int i = 0; i < 4; ++i)
      #pragma unroll
      for (int j = 0; j < 4; ++j) acc2[i][j] = bvp[j];
  }
  for (int k = 0; k < 256; k += 4) {
    float4 w0 = *reinterpret_cast<const float4*>(&W2[(k+0)*HH + 4*tx]);
    float4 w1 = *reinterpret_cast<const float4*>(&W2[(k+1)*HH + 4*tx]);
    float4 w2 = *reinterpret_cast<const float4*>(&W2[(k+2)*HH + 4*tx]);
    float4 w3 = *reinterpret_cast<const float4*>(&W2[(k+3)*HH + 4*tx]);
    const float* w0p = reinterpret_cast<const float*>(&w0);
    const float* w1p = reinterpret_cast<const float*>(&w1);
    const float* w2p = reinterpret_cast<const float*>(&w2);
    const float* w3p = reinterpret_cast<const float*>(&w3);
    #pragma unroll
    for (int i = 0; i < 4; ++i) {
      float4 iv = *reinterpret_cast<const float4*>(&h1[4*ty + i][k]);
      #pragma unroll
      for (int j = 0; j < 4; ++j)
        acc2[i][j] += iv.x*w0p[j] + iv.y*w1p[j] + iv.z*w2p[j] + iv.w*w3p[j];
    }
  }
  if (MODE == 0) {
    #pragma unroll
    for (int i = 0; i < 4; ++i) {
      int g = row0 + 4*ty + i;
      union { __hip_bfloat16 h[4]; uint2 u; } o;
      #pragma unroll
      for (int j = 0; j < 4; ++j) o.h[j] = __float2bfloat16(eluf(acc2[i][j]));
      *reinterpret_cast<uint2*>(&e2[(size_t)g*HH + 4*tx]) = o.u;
    }
  } else {
    #pragma unroll
    for (int i = 0; i < 4; ++i) {
      int g = row0 + 4*ty + i;
      float4 mv;
      mv.x = eluf(acc2[i][0]); mv.y = eluf(acc2[i][1]);
      mv.z = eluf(acc2[i][2]); mv.w = eluf(acc2[i][3]);
      *reinterpret_cast<float4*>(&ws[OFF_M2 + g*HH + 4*tx]) = mv;
    }
  }
}

// ---- per-feature sum / sumsq reductions ----
__global__ __launch_bounds__(256) void k_stats_bf16(const __hip_bfloat16* __restrict__ d,
                                                    int rpb, float* __restrict__ sums) {
  int col = threadIdx.x;
  size_t r0 = (size_t)blockIdx.x * rpb;
  float s = 0.f, q = 0.f;
  for (int r = 0; r < rpb; ++r) {
    float v = __bfloat162float(d[(r0 + r)*HH + col]);
    s += v; q += v * v;
  }
  atomicAdd(&sums[col], s);
  atomicAdd(&sums[256 + col], q);
}

__global__ __launch_bounds__(256) void k_stats_f32(const float* __restrict__ d,
                                                   int rpb, float* __restrict__ sums) {
  int col = threadIdx.x;
  size_t r0 = (size_t)blockIdx.x * rpb;
  float s = 0.f, q = 0.f;
  for (int r = 0; r < rpb; ++r) {
    float v = d[(r0 + r)*HH + col];
    s += v; q += v * v;
  }
  atomicAdd(&sums[col], s);
  atomicAdd(&sums[256 + col], q);
}

// ---- BN affine finalize: a = gamma*rstd, c = beta - mean*a ----
__global__ void k_bn_final(float* __restrict__ st, const float* __restrict__ g,
                           const float* __restrict__ be, float inv_n) {
  int c = threadIdx.x;
  float mean = st[c] * inv_n;
  float var  = fmaxf(st[256 + c] * inv_n - mean * mean, 0.f);
  float a = g[c] * rsqrtf(var + 1e-5f);
  st[512 + c] = a;
  st[768 + c] = be[c] - mean * a;
}

// ---- BN-fused edge->node aggregation. one block per (b,n) ----
__global__ __launch_bounds__(256) void k_agg(const __hip_bfloat16* __restrict__ e2,
                                             float* __restrict__ ws) {
  int col = threadIdx.x;
  int bn = blockIdx.x; int b = bn >> 6; int n = bn & 63;
  float a  = ws[OFF_STATS_E + 512 + col];
  float c0 = ws[OFF_STATS_E + 768 + col];
  const __hip_bfloat16* base = e2 + (size_t)b * EE * HH;
  float S = 0.f;
  for (int j = 0; j < 63; ++j)
    S += __bfloat162float(base[(size_t)(n*63 + j)*HH + col]);
  float T = 0.f;
  for (int i = 0; i < NN; ++i) {
    if (i == n) continue;
    int e = i*63 + n - (n > i ? 1 : 0);
    T += __bfloat162float(base[(size_t)e*HH + col]);
  }
  ws[OFF_NODES + bn*512 + col]       = a * S * (1.f/63.f) + c0;
  ws[OFF_NODES + bn*512 + 256 + col] = a * T * (1.f/63.f) + c0;
}

// ---- head: fused = [x, BN(m)] @ W_fuse + b ; rel = fused @ W_pred + b ; cumsum ----
__global__ __launch_bounds__(256) void k_head(const float* __restrict__ centers,
                                              const float* __restrict__ ws,
                                              const float* __restrict__ Wf,
                                              const float* __restrict__ bf,
                                              const float* __restrict__ Wp,
                                              const float* __restrict__ bp,
                                              float* __restrict__ out) {
  __shared__ float in2[512];
  __shared__ float fl[256];
  __shared__ float rl[60];
  int row = blockIdx.x, tid = threadIdx.x;
  in2[tid] = ws[OFF_X + row*HH + tid];
  float am = ws[OFF_STATS_M + 512 + tid], cm = ws[OFF_STATS_M + 768 + tid];
  in2[256 + tid] = am * ws[OFF_M2 + row*HH + tid] + cm;
  __syncthreads();
  float acc = bf[tid];
  for (int k = 0; k < 512; k += 4) {
    float4 iv = *reinterpret_cast<const float4*>(&in2[k]);
    acc += iv.x*Wf[(k+0)*HH + tid] + iv.y*Wf[(k+1)*HH + tid]
         + iv.z*Wf[(k+2)*HH + tid] + iv.w*Wf[(k+3)*HH + tid];
  }
  fl[tid] = acc;
  __syncthreads();
  if (tid < 60) {
    float a2 = bp[tid];
    for (int t = 0; t < 256; ++t) a2 += fl[t] * Wp[t*60 + tid];
    rl[tid] = a2;
    out[row*60 + tid] = a2;
  }
  __syncthreads();
  if (tid < 2) {
    float run = centers[(row*PREVN + 5)*2 + tid];
    #pragma unroll
    for (int p = 0; p < PREDN; ++p) {
      run += rl[2*p + tid];
      out[61440 + row*60 + 2*p + tid] = run;
    }
  }
}

extern "C" void kernel_launch(void* const* d_in, const int* in_sizes, int n_in,
                              void* d_out, int out_size, void* d_ws, size_t ws_size,
                              hipStream_t stream) {
  const float* centers = (const float*)d_in[0];
  // d_in[1]=rel_rec, d_in[2]=rel_send: fixed one-hots, index math replaces them
  const float* W_traj = (const float*)d_in[3];
  const float* b_traj = (const float*)d_in[4];
  const float* n2e_W1 = (const float*)d_in[5];
  const float* n2e_b1 = (const float*)d_in[6];
  const float* n2e_W2 = (const float*)d_in[7];
  const float* n2e_b2 = (const float*)d_in[8];
  const float* n2e_g  = (const float*)d_in[9];
  const float* n2e_be = (const float*)d_in[10];
  const float* e2n_W1 = (const float*)d_in[11];
  const float* e2n_b1 = (const float*)d_in[12];
  const float* e2n_W2 = (const float*)d_in[13];
  const float* e2n_b2 = (const float*)d_in[14];
  const float* e2n_g  = (const float*)d_in[15];
  const float* e2n_be = (const float*)d_in[16];
  const float* W_fuse = (const float*)d_in[17];
  const float* b_fuse = (const float*)d_in[18];
  const float* W_pred = (const float*)d_in[19];
  const float* b_pred = (const float*)d_in[20];

  float* ws = (float*)d_ws;
  __hip_bfloat16* e2 = (__hip_bfloat16*)((char*)d_ws + E2_BYTE_OFF);

  k_zero<<<8, 256, 0, stream>>>(ws);                       // stats_e + stats_m
  k_x<<<NROWS, 256, 0, stream>>>(centers, W_traj, b_traj, ws);
  k_mlp<0><<<EROWS/16, 256, 0, stream>>>(ws, n2e_W1, n2e_b1, n2e_W2, n2e_b2, e2);
  k_stats_bf16<<<1024, 256, 0, stream>>>(e2, 63, ws + OFF_STATS_E);
  k_bn_final<<<1, 256, 0, stream>>>(ws + OFF_STATS_E, n2e_g, n2e_be, 1.f / (float)EROWS);
  k_agg<<<NROWS, 256, 0, stream>>>(e2, ws);
  k_mlp<1><<<NROWS/16, 256, 0, stream>>>(ws, e2n_W1, e2n_b1, e2n_W2, e2n_b2, e2);
  k_stats_f32<<<64, 256, 0, stream>>>(ws + OFF_M2, 16, ws + OFF_STATS_M);
  k_bn_final<<<1, 256, 0, stream>>>(ws + OFF_STATS_M, e2n_g, e2n_be, 1.f / (float)NROWS);
  k_head<<<NROWS, 256, 0, stream>>>(centers, ws, W_fuse, b_fuse, W_pred, b_pred,
                                    (float*)d_out);
}

// Round 3
// 517.966 us; speedup vs baseline: 1.3206x; 1.3206x over previous
//
#include <hip/hip_runtime.h>
#include <hip/hip_bf16.h>

#define BB 16
#define NN 64
#define PREVN 6
#define PREDN 30
#define HH 256
#define EE 4032              // NN*(NN-1)
#define EROWS (BB*EE)        // 64512
#define NROWS (BB*NN)        // 1024

typedef short short8 __attribute__((ext_vector_type(8)));
typedef float f32x4 __attribute__((ext_vector_type(4)));

// ---- f32 workspace layout (float element offsets) ----
enum : int {
  OFF_STATS_E = 0,       // 1024: [0:256]=sum [256:512]=sumsq [512:768]=a [768:1024]=c
  OFF_STATS_M = 1024,    // 1024
  OFF_X       = 2048,    // 1024*256 f32 (k_head input)
  F32_END     = 264192
};
// ---- bf16 area (element offsets within wb = (bf16*)(ws + F32_END)) ----
enum : size_t {
  BO_XB    = 0,          // 1024*256
  BO_W1TE  = 262144,     // 256*512 (n2e W1^T)
  BO_W2TE  = 393216,     // 256*256
  BO_W1TN  = 458752,     // 256*512 (e2n W1^T)
  BO_W2TN  = 589824,     // 256*256
  BO_NODES = 655360,     // 1024*512
  BO_M2    = 1179648,    // 1024*256
  BO_E2    = 1441792     // 64512*256
};

__device__ __forceinline__ float eluf(float v) { return v > 0.f ? v : expm1f(v); }

__global__ void k_zero(float* __restrict__ p) {
  p[blockIdx.x * 256 + threadIdx.x] = 0.f;
}

// ---- transpose W (K x 256 f32, row-major) -> WT (256 x K bf16) ----
template<int K>
__global__ __launch_bounds__(256) void k_wt(const float* __restrict__ W,
                                            __hip_bfloat16* __restrict__ WT) {
  int idx = blockIdx.x * 256 + threadIdx.x;      // n*K + k
  int n = idx / K, k = idx - n * K;
  WT[idx] = __float2bfloat16(W[k * 256 + n]);
}

// ---- x = rel_pos @ W_traj + b_traj ; writes f32 (head) + bf16 (edge MLP) ----
__global__ __launch_bounds__(256) void k_x(const float* __restrict__ centers,
                                           const float* __restrict__ Wt,
                                           const float* __restrict__ bt,
                                           float* __restrict__ ws,
                                           __hip_bfloat16* __restrict__ xb) {
  int row = blockIdx.x, col = threadIdx.x;
  const float* c = centers + row * (PREVN * 2);
  float rp[12];
  #pragma unroll
  for (int t = 0; t < 5; ++t) {
    rp[2 + 2*t] = c[(t+1)*2 + 0] - c[t*2 + 0];
    rp[3 + 2*t] = c[(t+1)*2 + 1] - c[t*2 + 1];
  }
  float acc = bt[col];
  #pragma unroll
  for (int k = 2; k < 12; ++k) acc += rp[k] * Wt[k*HH + col];
  ws[OFF_X + row*HH + col] = acc;
  xb[row*HH + col] = __float2bfloat16(acc);
}

// ---- fused 2-layer MLP via MFMA 16x16x32 bf16. 64 rows/block, 4 waves.
//      MODE 0: edge (gather x rows via rc/sd). MODE 1: node (contiguous 512-wide rows).
//      Epilogue: BN stats atomics + vectorized bf16 store. ----
template<int MODE>
__global__ __launch_bounds__(256, 3) void k_mlp_mfma(
    const __hip_bfloat16* __restrict__ A,
    const __hip_bfloat16* __restrict__ W1T,   // 256 x 512, n-major
    const float* __restrict__ b1,
    const __hip_bfloat16* __restrict__ W2T,   // 256 x 256, n-major
    const float* __restrict__ b2,
    __hip_bfloat16* __restrict__ outp,
    float* __restrict__ stats) {
  __shared__ __hip_bfloat16 hs[64][264];      // +8 pad: 2-way bank alias only (free)
  const int tid = threadIdx.x;
  const int w = tid >> 6, lane = tid & 63;
  const int m16 = lane & 15, quad = lane >> 4;
  const int row0 = blockIdx.x * 64;
  const int g = row0 + w*16 + m16;            // this lane's A row
  const int ko = quad * 8;                    // lane's k sub-offset

  const __hip_bfloat16 *base0, *base1;
  if (MODE == 0) {
    int b = g / EE; int e = g - b * EE;
    int rc = e / 63; int jj = e - rc * 63;
    int sd = jj + (jj >= rc ? 1 : 0);
    base0 = A + (size_t)(b*NN + rc)*HH;       // k in [0,256): receiver row
    base1 = A + (size_t)(b*NN + sd)*HH;       // k in [256,512): sender row
  } else {
    base0 = A + (size_t)g * 512;
    base1 = base0 + 256;
  }

  // ---- layer 1: 64x512 @ 512x256 ----
  f32x4 acc[16];
  #pragma unroll
  for (int j = 0; j < 16; ++j) {
    float bv = b1[j*16 + m16];                // D col = lane&15
    acc[j] = (f32x4){bv, bv, bv, bv};
  }
  #pragma unroll
  for (int ks = 0; ks < 16; ++ks) {
    const __hip_bfloat16* ap = (ks < 8) ? (base0 + ks*32 + ko)
                                        : (base1 + (ks - 8)*32 + ko);
    short8 af = *reinterpret_cast<const short8*>(ap);
    #pragma unroll
    for (int j = 0; j < 16; ++j) {
      short8 bf = *reinterpret_cast<const short8*>(
          W1T + (size_t)(j*16 + m16)*512 + ks*32 + ko);
      acc[j] = __builtin_amdgcn_mfma_f32_16x16x32_bf16(af, bf, acc[j], 0, 0, 0);
    }
  }
  // ELU -> LDS (D: col=lane&15, row=quad*4+reg). Wave touches only its own 16 rows,
  // and layer-2 reads only its own rows -> no __syncthreads needed here.
  #pragma unroll
  for (int j = 0; j < 16; ++j)
    #pragma unroll
    for (int r = 0; r < 4; ++r)
      hs[w*16 + quad*4 + r][j*16 + m16] = __float2bfloat16(eluf(acc[j][r]));

  // ---- layer 2: 64x256 @ 256x256 ----
  f32x4 acc2[16];
  #pragma unroll
  for (int j = 0; j < 16; ++j) {
    float bv = b2[j*16 + m16];
    acc2[j] = (f32x4){bv, bv, bv, bv};
  }
  #pragma unroll
  for (int ks = 0; ks < 8; ++ks) {
    short8 af = *reinterpret_cast<const short8*>(&hs[w*16 + m16][ks*32 + ko]);
    #pragma unroll
    for (int j = 0; j < 16; ++j) {
      short8 bf = *reinterpret_cast<const short8*>(
          W2T + (size_t)(j*16 + m16)*256 + ks*32 + ko);
      acc2[j] = __builtin_amdgcn_mfma_f32_16x16x32_bf16(af, bf, acc2[j], 0, 0, 0);
    }
  }
  // ELU(h2) -> LDS (own rows again)
  #pragma unroll
  for (int j = 0; j < 16; ++j)
    #pragma unroll
    for (int r = 0; r < 4; ++r)
      hs[w*16 + quad*4 + r][j*16 + m16] = __float2bfloat16(eluf(acc2[j][r]));
  __syncthreads();   // epilogue reads all rows

  // ---- fused BN stats: col sums over this block's 64 rows ----
  {
    float s = 0.f, q = 0.f;
    #pragma unroll 8
    for (int r = 0; r < 64; ++r) {
      float v = __bfloat162float(hs[r][tid]);
      s += v; q += v * v;
    }
    atomicAdd(&stats[tid], s);
    atomicAdd(&stats[256 + tid], q);
  }

  // ---- vectorized bf16 store: 64x256 = 2048 uint4 ----
  #pragma unroll
  for (int i = 0; i < 8; ++i) {
    int u = i*256 + tid;
    int r = u >> 5, c = (u & 31) * 8;
    *reinterpret_cast<uint4*>(outp + (size_t)(row0 + r)*HH + c) =
        *reinterpret_cast<const uint4*>(&hs[r][c]);
  }
}

// ---- BN affine finalize: a = gamma*rstd, c = beta - mean*a ----
__global__ void k_bn_final(float* __restrict__ st, const float* __restrict__ g,
                           const float* __restrict__ be, float inv_n) {
  int c = threadIdx.x;
  float mean = st[c] * inv_n;
  float var  = fmaxf(st[256 + c] * inv_n - mean * mean, 0.f);
  float a = g[c] * rsqrtf(var + 1e-5f);
  st[512 + c] = a;
  st[768 + c] = be[c] - mean * a;
}

// ---- BN-fused edge->node aggregation, writes bf16 nodes. one block per (b,n) ----
__global__ __launch_bounds__(256) void k_agg(const __hip_bfloat16* __restrict__ e2,
                                             const float* __restrict__ st,
                                             __hip_bfloat16* __restrict__ nodes) {
  int col = threadIdx.x;
  int bn = blockIdx.x; int b = bn >> 6; int n = bn & 63;
  float a  = st[512 + col];
  float c0 = st[768 + col];
  const __hip_bfloat16* base = e2 + (size_t)b * EE * HH;
  float S = 0.f;
  for (int j = 0; j < 63; ++j)
    S += __bfloat162float(base[(size_t)(n*63 + j)*HH + col]);
  float T = 0.f;
  for (int i = 0; i < NN; ++i) {
    if (i == n) continue;
    int e = i*63 + n - (n > i ? 1 : 0);
    T += __bfloat162float(base[(size_t)e*HH + col]);
  }
  nodes[(size_t)bn*512 + col]       = __float2bfloat16(a * S * (1.f/63.f) + c0);
  nodes[(size_t)bn*512 + 256 + col] = __float2bfloat16(a * T * (1.f/63.f) + c0);
}

// ---- head: fused = [x, BN(m)] @ W_fuse + b ; rel = fused @ W_pred + b ; cumsum ----
__global__ __launch_bounds__(256) void k_head(const float* __restrict__ centers,
                                              const float* __restrict__ ws,
                                              const __hip_bfloat16* __restrict__ m2b,
                                              const float* __restrict__ Wf,
                                              const float* __restrict__ bf,
                                              const float* __restrict__ Wp,
                                              const float* __restrict__ bp,
                                              float* __restrict__ out) {
  __shared__ float in2[512];
  __shared__ float fl[256];
  __shared__ float rl[60];
  int row = blockIdx.x, tid = threadIdx.x;
  in2[tid] = ws[OFF_X + row*HH + tid];
  float am = ws[OFF_STATS_M + 512 + tid], cm = ws[OFF_STATS_M + 768 + tid];
  in2[256 + tid] = am * __bfloat162float(m2b[(size_t)row*HH + tid]) + cm;
  __syncthreads();
  float acc = bf[tid];
  for (int k = 0; k < 512; k += 4) {
    float4 iv = *reinterpret_cast<const float4*>(&in2[k]);
    acc += iv.x*Wf[(k+0)*HH + tid] + iv.y*Wf[(k+1)*HH + tid]
         + iv.z*Wf[(k+2)*HH + tid] + iv.w*Wf[(k+3)*HH + tid];
  }
  fl[tid] = acc;
  __syncthreads();
  if (tid < 60) {
    float a2 = bp[tid];
    for (int t = 0; t < 256; ++t) a2 += fl[t] * Wp[t*60 + tid];
    rl[tid] = a2;
    out[row*60 + tid] = a2;
  }
  __syncthreads();
  if (tid < 2) {
    float run = centers[(row*PREVN + 5)*2 + tid];
    #pragma unroll
    for (int p = 0; p < PREDN; ++p) {
      run += rl[2*p + tid];
      out[61440 + row*60 + 2*p + tid] = run;
    }
  }
}

extern "C" void kernel_launch(void* const* d_in, const int* in_sizes, int n_in,
                              void* d_out, int out_size, void* d_ws, size_t ws_size,
                              hipStream_t stream) {
  const float* centers = (const float*)d_in[0];
  const float* W_traj = (const float*)d_in[3];
  const float* b_traj = (const float*)d_in[4];
  const float* n2e_W1 = (const float*)d_in[5];
  const float* n2e_b1 = (const float*)d_in[6];
  const float* n2e_W2 = (const float*)d_in[7];
  const float* n2e_b2 = (const float*)d_in[8];
  const float* n2e_g  = (const float*)d_in[9];
  const float* n2e_be = (const float*)d_in[10];
  const float* e2n_W1 = (const float*)d_in[11];
  const float* e2n_b1 = (const float*)d_in[12];
  const float* e2n_W2 = (const float*)d_in[13];
  const float* e2n_b2 = (const float*)d_in[14];
  const float* e2n_g  = (const float*)d_in[15];
  const float* e2n_be = (const float*)d_in[16];
  const float* W_fuse = (const float*)d_in[17];
  const float* b_fuse = (const float*)d_in[18];
  const float* W_pred = (const float*)d_in[19];
  const float* b_pred = (const float*)d_in[20];

  float* ws = (float*)d_ws;
  __hip_bfloat16* wb = (__hip_bfloat16*)(ws + F32_END);

  k_zero<<<8, 256, 0, stream>>>(ws);
  k_x<<<NROWS, 256, 0, stream>>>(centers, W_traj, b_traj, ws, wb + BO_XB);
  k_wt<512><<<512, 256, 0, stream>>>(n2e_W1, wb + BO_W1TE);
  k_wt<256><<<256, 256, 0, stream>>>(n2e_W2, wb + BO_W2TE);
  k_wt<512><<<512, 256, 0, stream>>>(e2n_W1, wb + BO_W1TN);
  k_wt<256><<<256, 256, 0, stream>>>(e2n_W2, wb + BO_W2TN);

  k_mlp_mfma<0><<<EROWS/64, 256, 0, stream>>>(wb + BO_XB, wb + BO_W1TE, n2e_b1,
                                              wb + BO_W2TE, n2e_b2,
                                              wb + BO_E2, ws + OFF_STATS_E);
  k_bn_final<<<1, 256, 0, stream>>>(ws + OFF_STATS_E, n2e_g, n2e_be, 1.f/(float)EROWS);
  k_agg<<<NROWS, 256, 0, stream>>>(wb + BO_E2, ws + OFF_STATS_E, wb + BO_NODES);
  k_mlp_mfma<1><<<NROWS/64, 256, 0, stream>>>(wb + BO_NODES, wb + BO_W1TN, e2n_b1,
                                              wb + BO_W2TN, e2n_b2,
                                              wb + BO_M2, ws + OFF_STATS_M);
  k_bn_final<<<1, 256, 0, stream>>>(ws + OFF_STATS_M, e2n_g, e2n_be, 1.f/(float)NROWS);
  k_head<<<NROWS, 256, 0, stream>>>(centers, ws, wb + BO_M2, W_fuse, b_fuse,
                                    W_pred, b_pred, (float*)d_out);
}

// Round 4
// 323.578 us; speedup vs baseline: 2.1139x; 1.6007x over previous
//
#include <hip/hip_runtime.h>
#include <hip/hip_bf16.h>

#define BB 16
#define NN 64
#define PREVN 6
#define PREDN 30
#define HH 256
#define EE 4032              // NN*(NN-1)
#define EROWS (BB*EE)        // 64512
#define NROWS (BB*NN)        // 1024

typedef short short8 __attribute__((ext_vector_type(8)));
typedef float f32x4 __attribute__((ext_vector_type(4)));

// ---- f32 workspace layout (float element offsets) ----
enum : int {
  OFF_STATS_E = 0,       // 1024: [0:256]=sum [256:512]=sumsq [512:768]=a [768:1024]=c
  OFF_STATS_M = 1024,    // 1024
  OFF_X       = 2048,    // (unused by head now, kept for debug headroom)
  F32_END     = 264192
};
// ---- bf16 area (element offsets within wb = (bf16*)(ws + F32_END)) ----
enum : size_t {
  BO_XB    = 0,          // 1024*256
  BO_W1TE  = 262144,     // 256*512 (n2e W1^T)
  BO_W2TE  = 393216,     // 256*256
  BO_W1TN  = 458752,     // 256*512 (e2n W1^T)
  BO_W2TN  = 589824,     // 256*256
  BO_WFT   = 655360,     // 256*512 (W_fuse^T)
  BO_WPT   = 786432,     // 64*256  (W_pred^T, zero-padded cols 60..63)
  BO_NODES = 802816,     // 1024*512 (also reused as `fin` for the head)
  BO_M2    = 1327104,    // 1024*256
  BO_E2    = 1589248     // 64512*256
};

__device__ __forceinline__ float eluf(float v) { return v > 0.f ? v : expm1f(v); }

__global__ void k_zero(float* __restrict__ p) {
  p[blockIdx.x * 256 + threadIdx.x] = 0.f;
}

// ---- LDS-tiled transpose: W (K x 256 f32) -> WT (256 x K bf16), coalesced both sides ----
template<int K>
__global__ __launch_bounds__(256) void k_wt(const float* __restrict__ W,
                                            __hip_bfloat16* __restrict__ WT) {
  __shared__ float t[64][65];
  const int KB = K / 64;
  int bk = blockIdx.x % KB, bn = blockIdx.x / KB;
  int k0 = bk * 64, n0 = bn * 64;
  int tx = threadIdx.x & 63, ty = threadIdx.x >> 6;
  #pragma unroll
  for (int i = 0; i < 16; ++i)
    t[ty + i*4][tx] = W[(size_t)(k0 + ty + i*4) * 256 + n0 + tx];
  __syncthreads();
  #pragma unroll
  for (int i = 0; i < 16; ++i)
    WT[(size_t)(n0 + ty + i*4) * K + k0 + tx] = __float2bfloat16(t[tx][ty + i*4]);
}

// ---- W_pred (256 x 60 f32) -> WpT (64 x 256 bf16), zero-padded ----
__global__ __launch_bounds__(256) void k_wpt(const float* __restrict__ Wp,
                                             __hip_bfloat16* __restrict__ WpT) {
  int idx = blockIdx.x * 256 + threadIdx.x;   // c*256 + k
  int c = idx >> 8, k = idx & 255;
  WpT[idx] = __float2bfloat16(c < 60 ? Wp[k * 60 + c] : 0.f);
}

// ---- x = rel_pos @ W_traj + b_traj ; bf16 out ----
__global__ __launch_bounds__(256) void k_x(const float* __restrict__ centers,
                                           const float* __restrict__ Wt,
                                           const float* __restrict__ bt,
                                           __hip_bfloat16* __restrict__ xb) {
  int row = blockIdx.x, col = threadIdx.x;
  const float* c = centers + row * (PREVN * 2);
  float rp[12];
  #pragma unroll
  for (int t = 0; t < 5; ++t) {
    rp[2 + 2*t] = c[(t+1)*2 + 0] - c[t*2 + 0];
    rp[3 + 2*t] = c[(t+1)*2 + 1] - c[t*2 + 1];
  }
  float acc = bt[col];
  #pragma unroll
  for (int k = 2; k < 12; ++k) acc += rp[k] * Wt[k*HH + col];
  xb[row*HH + col] = __float2bfloat16(acc);
}

// ---- fused 2-layer MLP via MFMA 16x16x32 bf16.
//      Block = 64 rows, 4 waves; wave = 64 rows x 64-col stripe (4 mt x 4 jt).
//      A/B fragments each reused 4x -> load:MFMA = 0.5.
//      MODE 0: edge (gather x rows). MODE 1: node (contiguous 512-wide rows). ----
template<int MODE>
__global__ __launch_bounds__(256, 3) void k_mlp_mfma(
    const __hip_bfloat16* __restrict__ A,
    const __hip_bfloat16* __restrict__ W1T,   // 256 x 512, n-major
    const float* __restrict__ b1,
    const __hip_bfloat16* __restrict__ W2T,   // 256 x 256, n-major
    const float* __restrict__ b2,
    __hip_bfloat16* __restrict__ outp,
    float* __restrict__ stats) {
  __shared__ __hip_bfloat16 hs[64][264];      // stride 528B: 16B-aligned rows
  const int tid = threadIdx.x;
  const int w = tid >> 6, lane = tid & 63;
  const int m16 = lane & 15, quad = lane >> 4;
  const int ko = quad * 8;
  const int row0 = blockIdx.x * 64;
  const int colw = w * 64;

  const __hip_bfloat16 *ba0[4], *ba1[4];
  #pragma unroll
  for (int mt = 0; mt < 4; ++mt) {
    int g = row0 + mt*16 + m16;
    if (MODE == 0) {
      int b = g / EE; int e = g - b * EE;
      int rc = e / 63; int jj = e - rc * 63;
      int sd = jj + (jj >= rc ? 1 : 0);
      ba0[mt] = A + (size_t)(b*NN + rc)*HH;
      ba1[mt] = A + (size_t)(b*NN + sd)*HH;
    } else {
      ba0[mt] = A + (size_t)g * 512;
      ba1[mt] = ba0[mt] + 256;
    }
  }

  // ---- layer 1: 64x512 @ 512x256 ----
  f32x4 acc[4][4];
  #pragma unroll
  for (int jt = 0; jt < 4; ++jt) {
    float bv = b1[colw + jt*16 + m16];
    #pragma unroll
    for (int mt = 0; mt < 4; ++mt) acc[mt][jt] = (f32x4){bv, bv, bv, bv};
  }
  #pragma unroll
  for (int ks = 0; ks < 16; ++ks) {
    short8 af[4], bf[4];
    #pragma unroll
    for (int mt = 0; mt < 4; ++mt)
      af[mt] = *reinterpret_cast<const short8*>(
          (ks < 8 ? ba0[mt] + ks*32 : ba1[mt] + (ks-8)*32) + ko);
    #pragma unroll
    for (int jt = 0; jt < 4; ++jt)
      bf[jt] = *reinterpret_cast<const short8*>(
          W1T + (size_t)(colw + jt*16 + m16)*512 + ks*32 + ko);
    #pragma unroll
    for (int mt = 0; mt < 4; ++mt)
      #pragma unroll
      for (int jt = 0; jt < 4; ++jt)
        acc[mt][jt] = __builtin_amdgcn_mfma_f32_16x16x32_bf16(af[mt], bf[jt],
                                                              acc[mt][jt], 0, 0, 0);
  }
  // ELU(h1) -> LDS (D: col=lane&15, row=quad*4+reg)
  #pragma unroll
  for (int mt = 0; mt < 4; ++mt)
    #pragma unroll
    for (int jt = 0; jt < 4; ++jt)
      #pragma unroll
      for (int r = 0; r < 4; ++r)
        hs[mt*16 + quad*4 + r][colw + jt*16 + m16] =
            __float2bfloat16(eluf(acc[mt][jt][r]));
  __syncthreads();

  // ---- layer 2: 64x256 @ 256x256 ----
  f32x4 acc2[4][4];
  #pragma unroll
  for (int jt = 0; jt < 4; ++jt) {
    float bv = b2[colw + jt*16 + m16];
    #pragma unroll
    for (int mt = 0; mt < 4; ++mt) acc2[mt][jt] = (f32x4){bv, bv, bv, bv};
  }
  #pragma unroll
  for (int ks = 0; ks < 8; ++ks) {
    short8 af[4], bf[4];
    #pragma unroll
    for (int mt = 0; mt < 4; ++mt)
      af[mt] = *reinterpret_cast<const short8*>(&hs[mt*16 + m16][ks*32 + ko]);
    #pragma unroll
    for (int jt = 0; jt < 4; ++jt)
      bf[jt] = *reinterpret_cast<const short8*>(
          W2T + (size_t)(colw + jt*16 + m16)*256 + ks*32 + ko);
    #pragma unroll
    for (int mt = 0; mt < 4; ++mt)
      #pragma unroll
      for (int jt = 0; jt < 4; ++jt)
        acc2[mt][jt] = __builtin_amdgcn_mfma_f32_16x16x32_bf16(af[mt], bf[jt],
                                                               acc2[mt][jt], 0, 0, 0);
  }
  __syncthreads();   // all h1 reads done before hs is overwritten with h2
  #pragma unroll
  for (int mt = 0; mt < 4; ++mt)
    #pragma unroll
    for (int jt = 0; jt < 4; ++jt)
      #pragma unroll
      for (int r = 0; r < 4; ++r)
        hs[mt*16 + quad*4 + r][colw + jt*16 + m16] =
            __float2bfloat16(eluf(acc2[mt][jt][r]));
  __syncthreads();

  // ---- fused BN stats over this block's 64 rows ----
  {
    float s = 0.f, q = 0.f;
    #pragma unroll 8
    for (int r = 0; r < 64; ++r) {
      float v = __bfloat162float(hs[r][tid]);
      s += v; q += v * v;
    }
    atomicAdd(&stats[tid], s);
    atomicAdd(&stats[256 + tid], q);
  }

  // ---- vectorized bf16 store: 64x256 = 2048 uint4 ----
  #pragma unroll
  for (int i = 0; i < 8; ++i) {
    int u = i*256 + tid;
    int r = u >> 5, c = (u & 31) * 8;
    *reinterpret_cast<uint4*>(outp + (size_t)(row0 + r)*HH + c) =
        *reinterpret_cast<const uint4*>(&hs[r][c]);
  }
}

// ---- BN affine finalize: a = gamma*rstd, c = beta - mean*a ----
__global__ void k_bn_final(float* __restrict__ st, const float* __restrict__ g,
                           const float* __restrict__ be, float inv_n) {
  int c = threadIdx.x;
  float mean = st[c] * inv_n;
  float var  = fmaxf(st[256 + c] * inv_n - mean * mean, 0.f);
  float a = g[c] * rsqrtf(var + 1e-5f);
  st[512 + c] = a;
  st[768 + c] = be[c] - mean * a;
}

// ---- BN-fused edge->node aggregation (bf162 vectorized; S/T split by half-block) ----
__global__ __launch_bounds__(256) void k_agg(const __hip_bfloat16* __restrict__ e2,
                                             const float* __restrict__ st,
                                             __hip_bfloat16* __restrict__ nodes) {
  int tid = threadIdx.x;
  int c2 = (tid & 127) * 2, half = tid >> 7;
  int bn = blockIdx.x; int b = bn >> 6; int n = bn & 63;
  const __hip_bfloat16* base = e2 + (size_t)b * EE * HH;
  float s0 = 0.f, s1 = 0.f;
  if (half == 0) {
    for (int j = 0; j < 63; ++j) {
      __hip_bfloat162 v = *reinterpret_cast<const __hip_bfloat162*>(
          base + (size_t)(n*63 + j)*HH + c2);
      s0 += __bfloat162float(v.x); s1 += __bfloat162float(v.y);
    }
  } else {
    for (int i = 0; i < NN; ++i) {
      if (i == n) continue;
      int e = i*63 + n - (n > i ? 1 : 0);
      __hip_bfloat162 v = *reinterpret_cast<const __hip_bfloat162*>(
          base + (size_t)e*HH + c2);
      s0 += __bfloat162float(v.x); s1 += __bfloat162float(v.y);
    }
  }
  float a0 = st[512 + c2], a1 = st[512 + c2 + 1];
  float k0 = st[768 + c2], k1 = st[768 + c2 + 1];
  __hip_bfloat162 o;
  o.x = __float2bfloat16(a0 * s0 * (1.f/63.f) + k0);
  o.y = __float2bfloat16(a1 * s1 * (1.f/63.f) + k1);
  *reinterpret_cast<__hip_bfloat162*>(nodes + (size_t)bn*512 + half*256 + c2) = o;
}

// ---- build fin = [xb, BN(m2)] (1024 x 512 bf16), reusing the nodes buffer ----
__global__ __launch_bounds__(256) void k_bnm(const __hip_bfloat16* __restrict__ xb,
                                             const __hip_bfloat16* __restrict__ m2,
                                             const float* __restrict__ st,
                                             __hip_bfloat16* __restrict__ fin) {
  int row = blockIdx.x, tid = threadIdx.x;
  fin[(size_t)row*512 + tid] = xb[(size_t)row*256 + tid];
  float am = st[512 + tid], cm = st[768 + tid];
  float v = __bfloat162float(m2[(size_t)row*256 + tid]);
  fin[(size_t)row*512 + 256 + tid] = __float2bfloat16(am * v + cm);
}

// ---- head via MFMA: fused = fin @ WfT^T + bf (no act), rel = fused @ WpT^T + bp,
//      then per-row cumsum. Block = 64 rows, 4 waves (col stripes for fuse). ----
__global__ __launch_bounds__(256) void k_head_mfma(
    const __hip_bfloat16* __restrict__ fin,   // 1024 x 512
    const __hip_bfloat16* __restrict__ WfT,   // 256 x 512
    const float* __restrict__ bfv,
    const __hip_bfloat16* __restrict__ WpT,   // 64 x 256 (zero-padded)
    const float* __restrict__ bp,
    const float* __restrict__ centers,
    float* __restrict__ out) {
  __shared__ __hip_bfloat16 hs[64][264];
  __shared__ float rl[64][64];
  const int tid = threadIdx.x;
  const int w = tid >> 6, lane = tid & 63;
  const int m16 = lane & 15, quad = lane >> 4;
  const int ko = quad * 8;
  const int row0 = blockIdx.x * 64;
  const int colw = w * 64;

  // fuse layer: 64x512 @ 512x256
  f32x4 acc[4][4];
  #pragma unroll
  for (int jt = 0; jt < 4; ++jt) {
    float bv = bfv[colw + jt*16 + m16];
    #pragma unroll
    for (int mt = 0; mt < 4; ++mt) acc[mt][jt] = (f32x4){bv, bv, bv, bv};
  }
  #pragma unroll
  for (int ks = 0; ks < 16; ++ks) {
    short8 af[4], bf[4];
    #pragma unroll
    for (int mt = 0; mt < 4; ++mt)
      af[mt] = *reinterpret_cast<const short8*>(
          fin + (size_t)(row0 + mt*16 + m16)*512 + ks*32 + ko);
    #pragma unroll
    for (int jt = 0; jt < 4; ++jt)
      bf[jt] = *reinterpret_cast<const short8*>(
          WfT + (size_t)(colw + jt*16 + m16)*512 + ks*32 + ko);
    #pragma unroll
    for (int mt = 0; mt < 4; ++mt)
      #pragma unroll
      for (int jt = 0; jt < 4; ++jt)
        acc[mt][jt] = __builtin_amdgcn_mfma_f32_16x16x32_bf16(af[mt], bf[jt],
                                                              acc[mt][jt], 0, 0, 0);
  }
  #pragma unroll
  for (int mt = 0; mt < 4; ++mt)
    #pragma unroll
    for (int jt = 0; jt < 4; ++jt)
      #pragma unroll
      for (int r = 0; r < 4; ++r)
        hs[mt*16 + quad*4 + r][colw + jt*16 + m16] =
            __float2bfloat16(acc[mt][jt][r]);          // no activation
  __syncthreads();

  // pred layer: 64x256 @ 256x64 (wave 0 only)
  if (w == 0) {
    f32x4 acc2[4][4];
    #pragma unroll
    for (int jt = 0; jt < 4; ++jt) {
      int c = jt*16 + m16;
      float bv = (c < 60) ? bp[c] : 0.f;
      #pragma unroll
      for (int mt = 0; mt < 4; ++mt) acc2[mt][jt] = (f32x4){bv, bv, bv, bv};
    }
    #pragma unroll
    for (int ks = 0; ks < 8; ++ks) {
      short8 af[4], bf[4];
      #pragma unroll
      for (int mt = 0; mt < 4; ++mt)
        af[mt] = *reinterpret_cast<const short8*>(&hs[mt*16 + m16][ks*32 + ko]);
      #pragma unroll
      for (int jt = 0; jt < 4; ++jt)
        bf[jt] = *reinterpret_cast<const short8*>(
            WpT + (size_t)(jt*16 + m16)*256 + ks*32 + ko);
      #pragma unroll
      for (int mt = 0; mt < 4; ++mt)
        #pragma unroll
        for (int jt = 0; jt < 4; ++jt)
          acc2[mt][jt] = __builtin_amdgcn_mfma_f32_16x16x32_bf16(af[mt], bf[jt],
                                                                 acc2[mt][jt], 0, 0, 0);
    }
    #pragma unroll
    for (int mt = 0; mt < 4; ++mt)
      #pragma unroll
      for (int jt = 0; jt < 4; ++jt) {
        int c = jt*16 + m16;
        #pragma unroll
        for (int r = 0; r < 4; ++r) {
          int lr = mt*16 + quad*4 + r;
          rl[lr][c] = acc2[mt][jt][r];
          if (c < 60) out[(size_t)(row0 + lr)*60 + c] = acc2[mt][jt][r];
        }
      }
  }
  __syncthreads();

  // cumsum: 128 threads, one per (row, x/y)
  if (tid < 128) {
    int lr = tid >> 1, xy = tid & 1;
    int grow = row0 + lr;
    float run = centers[(size_t)(grow*PREVN + 5)*2 + xy];
    #pragma unroll
    for (int p = 0; p < PREDN; ++p) {
      run += rl[lr][2*p + xy];
      out[61440 + (size_t)grow*60 + 2*p + xy] = run;
    }
  }
}

extern "C" void kernel_launch(void* const* d_in, const int* in_sizes, int n_in,
                              void* d_out, int out_size, void* d_ws, size_t ws_size,
                              hipStream_t stream) {
  const float* centers = (const float*)d_in[0];
  const float* W_traj = (const float*)d_in[3];
  const float* b_traj = (const float*)d_in[4];
  const float* n2e_W1 = (const float*)d_in[5];
  const float* n2e_b1 = (const float*)d_in[6];
  const float* n2e_W2 = (const float*)d_in[7];
  const float* n2e_b2 = (const float*)d_in[8];
  const float* n2e_g  = (const float*)d_in[9];
  const float* n2e_be = (const float*)d_in[10];
  const float* e2n_W1 = (const float*)d_in[11];
  const float* e2n_b1 = (const float*)d_in[12];
  const float* e2n_W2 = (const float*)d_in[13];
  const float* e2n_b2 = (const float*)d_in[14];
  const float* e2n_g  = (const float*)d_in[15];
  const float* e2n_be = (const float*)d_in[16];
  const float* W_fuse = (const float*)d_in[17];
  const float* b_fuse = (const float*)d_in[18];
  const float* W_pred = (const float*)d_in[19];
  const float* b_pred = (const float*)d_in[20];

  float* ws = (float*)d_ws;
  __hip_bfloat16* wb = (__hip_bfloat16*)(ws + F32_END);

  k_zero<<<8, 256, 0, stream>>>(ws);
  k_x<<<NROWS, 256, 0, stream>>>(centers, W_traj, b_traj, wb + BO_XB);
  k_wt<512><<<32, 256, 0, stream>>>(n2e_W1, wb + BO_W1TE);
  k_wt<256><<<16, 256, 0, stream>>>(n2e_W2, wb + BO_W2TE);
  k_wt<512><<<32, 256, 0, stream>>>(e2n_W1, wb + BO_W1TN);
  k_wt<256><<<16, 256, 0, stream>>>(e2n_W2, wb + BO_W2TN);
  k_wt<512><<<32, 256, 0, stream>>>(W_fuse, wb + BO_WFT);
  k_wpt<<<64, 256, 0, stream>>>(W_pred, wb + BO_WPT);

  k_mlp_mfma<0><<<EROWS/64, 256, 0, stream>>>(wb + BO_XB, wb + BO_W1TE, n2e_b1,
                                              wb + BO_W2TE, n2e_b2,
                                              wb + BO_E2, ws + OFF_STATS_E);
  k_bn_final<<<1, 256, 0, stream>>>(ws + OFF_STATS_E, n2e_g, n2e_be, 1.f/(float)EROWS);
  k_agg<<<NROWS, 256, 0, stream>>>(wb + BO_E2, ws + OFF_STATS_E, wb + BO_NODES);
  k_mlp_mfma<1><<<NROWS/64, 256, 0, stream>>>(wb + BO_NODES, wb + BO_W1TN, e2n_b1,
                                              wb + BO_W2TN, e2n_b2,
                                              wb + BO_M2, ws + OFF_STATS_M);
  k_bn_final<<<1, 256, 0, stream>>>(ws + OFF_STATS_M, e2n_g, e2n_be, 1.f/(float)NROWS);
  k_bnm<<<NROWS, 256, 0, stream>>>(wb + BO_XB, wb + BO_M2, ws + OFF_STATS_M,
                                   wb + BO_NODES);
  k_head_mfma<<<NROWS/64, 256, 0, stream>>>(wb + BO_NODES, wb + BO_WFT, b_fuse,
                                            wb + BO_WPT, b_pred, centers,
                                            (float*)d_out);
}

// Round 5
// 237.220 us; speedup vs baseline: 2.8835x; 1.3640x over previous
//
#include <hip/hip_runtime.h>
#include <hip/hip_bf16.h>

#define BB 16
#define NN 64
#define PREVN 6
#define PREDN 30
#define HH 256
#define EE 4032              // NN*(NN-1)
#define EROWS (BB*EE)        // 64512
#define NROWS (BB*NN)        // 1024

typedef short short8 __attribute__((ext_vector_type(8)));
typedef float f32x4 __attribute__((ext_vector_type(4)));

// ---- f32 workspace layout (float element offsets) ----
enum : int {
  OFF_STATS_E = 0,       // 1024: [0:256]=sum [256:512]=sumsq
  OFF_STATS_M = 1024,    // 1024
  F32_END     = 264192
};
// ---- bf16 area (element offsets within wb = (bf16*)(ws + F32_END)) ----
enum : size_t {
  BO_XB    = 0,          // 1024*256
  BO_W1TE  = 262144,     // 256*512 (n2e W1^T)
  BO_W2TE  = 393216,     // 256*256
  BO_W1TN  = 458752,     // 256*512 (e2n W1^T)
  BO_W2TN  = 589824,     // 256*256
  BO_WFT   = 655360,     // 256*512 (W_fuse^T)
  BO_WPT   = 786432,     // 64*256  (W_pred^T, zero-padded cols 60..63)
  BO_NODES = 802816,     // 1024*512 (also reused as `fin` for the head)
  BO_M2    = 1327104,    // 1024*256
  BO_E2    = 1589248     // 64512*256
};

__device__ __forceinline__ float eluf(float v) { return v > 0.f ? v : expm1f(v); }

// async global -> LDS, 16 B per lane; LDS dest = wave-uniform base + lane*16
__device__ __forceinline__ void gl2lds16(const void* g, void* l) {
  __builtin_amdgcn_global_load_lds(
      (const __attribute__((address_space(1))) void*)g,
      (__attribute__((address_space(3))) void*)l, 16, 0, 0);
}

// ================= consolidated prep: transposes + wpt + zero + x-embed ==========
struct PrepArgs {
  const float *centers, *W_traj, *b_traj;
  const float *n2e_W1, *n2e_W2, *e2n_W1, *e2n_W2, *W_fuse, *W_pred;
  float* stats;                    // 2048 floats -> zero
  __hip_bfloat16 *xb, *w1te, *w2te, *w1tn, *w2tn, *wft, *wpt;
};

__global__ __launch_bounds__(256) void k_prep(PrepArgs a) {
  __shared__ float t[64][65];
  const int bid = blockIdx.x, tid = threadIdx.x;
  if (bid < 128) {                 // LDS-tiled W transposes (f32 KxN -> bf16 NxK)
    const float* W; __hip_bfloat16* WT; int K, lb;
    if (bid < 32)      { W = a.n2e_W1; WT = a.w1te; K = 512; lb = bid; }
    else if (bid < 48) { W = a.n2e_W2; WT = a.w2te; K = 256; lb = bid - 32; }
    else if (bid < 80) { W = a.e2n_W1; WT = a.w1tn; K = 512; lb = bid - 48; }
    else if (bid < 96) { W = a.e2n_W2; WT = a.w2tn; K = 256; lb = bid - 80; }
    else               { W = a.W_fuse; WT = a.wft;  K = 512; lb = bid - 96; }
    int KB = K / 64;
    int k0 = (lb % KB) * 64, n0 = (lb / KB) * 64;
    int tx = tid & 63, ty = tid >> 6;
    #pragma unroll
    for (int i = 0; i < 16; ++i)
      t[ty + i*4][tx] = W[(size_t)(k0 + ty + i*4) * 256 + n0 + tx];
    __syncthreads();
    #pragma unroll
    for (int i = 0; i < 16; ++i)
      WT[(size_t)(n0 + ty + i*4) * K + k0 + tx] = __float2bfloat16(t[tx][ty + i*4]);
  } else if (bid < 192) {          // W_pred (256x60) -> WpT (64x256, zero-padded)
    int idx = (bid - 128) * 256 + tid;
    int c = idx >> 8, k = idx & 255;
    a.wpt[idx] = __float2bfloat16(c < 60 ? a.W_pred[k * 60 + c] : 0.f);
  } else if (bid < 200) {          // zero stats
    a.stats[(bid - 192) * 256 + tid] = 0.f;
  } else {                         // x = rel_pos @ W_traj + b_traj
    int row = bid - 200, col = tid;
    const float* c = a.centers + row * (PREVN * 2);
    float rp[12];
    #pragma unroll
    for (int t2 = 0; t2 < 5; ++t2) {
      rp[2 + 2*t2] = c[(t2+1)*2 + 0] - c[t2*2 + 0];
      rp[3 + 2*t2] = c[(t2+1)*2 + 1] - c[t2*2 + 1];
    }
    float acc = a.b_traj[col];
    #pragma unroll
    for (int k = 2; k < 12; ++k) acc += rp[k] * a.W_traj[k*HH + col];
    a.xb[row*HH + col] = __float2bfloat16(acc);
  }
}

// ================= fused 2-layer MLP, LDS-staged MFMA ==========================
// Block = MT*16 rows x 256 cols, 4 waves, wave stripe = 64 cols.
// W-tiles (BK=64) + A-tile staged via global_load_lds into XOR-swizzled LDS;
// h1 lives in LDS; BN stats fused into epilogue.
template<int MODE>   // 0: edge (MT=4, gathered A rows), 1: node (MT=1, linear rows)
__global__ __launch_bounds__(256, 2) void k_mlp3(
    const __hip_bfloat16* __restrict__ A,
    const __hip_bfloat16* __restrict__ W1T,   // 256 x 512, n-major
    const float* __restrict__ b1,
    const __hip_bfloat16* __restrict__ W2T,   // 256 x 256, n-major
    const float* __restrict__ b2,
    __hip_bfloat16* __restrict__ outp,
    float* __restrict__ stats) {
  constexpr int MT = (MODE == 0) ? 4 : 1;
  constexpr int ROWS = MT * 16;
  __shared__ alignas(16) __hip_bfloat16 Wt[256 * 64];     // 32 KB, [col]*64k, swizzled
  __shared__ alignas(16) __hip_bfloat16 At[ROWS * 64];    // [row]*64k, swizzled
  __shared__ alignas(16) __hip_bfloat16 h1s[ROWS][264];
  const int tid = threadIdx.x;
  const int w = tid >> 6, lane = tid & 63;
  const int m16 = lane & 15, quad = lane >> 4;
  const int ko = quad * 8;
  const int row0 = blockIdx.x * ROWS;
  const int colw = w * 64;
  const int csub = lane >> 3, jl = lane & 7;
  const int jsrc = jl ^ csub;                 // source 16B-chunk for XOR-swizzled slot

  // A-staging row base pointers (issue i covers rows i*8..i*8+8; wave w does i=w,w+4)
  const __hip_bfloat16 *ar0[2], *ar1[2];
  #pragma unroll
  for (int t = 0; t < 2; ++t) {
    int i = w + 4 * t;
    if (i < MT * 2) {
      int r = i * 8 + csub;
      int g = row0 + r;
      if (MODE == 0) {
        int b = g / EE; int e = g - b * EE;
        int rc = e / 63; int jj = e - rc * 63;
        int sd = jj + (jj >= rc ? 1 : 0);
        ar0[t] = A + (size_t)(b * NN + rc) * HH;
        ar1[t] = A + (size_t)(b * NN + sd) * HH;
      } else {
        ar0[t] = A + (size_t)g * 512;
        ar1[t] = ar0[t] + 256;
      }
    }
  }
  const int swz0 = ((quad)     ^ (m16 & 7)) * 16;   // ks=0 chunk byte offset
  const int swz1 = ((quad + 4) ^ (m16 & 7)) * 16;   // ks=1

  // ---- layer 1: ROWSx512 @ 512x256 ----
  f32x4 acc[MT][4];
  #pragma unroll
  for (int jt = 0; jt < 4; ++jt) {
    float bv = b1[colw + jt*16 + m16];
    #pragma unroll
    for (int mt = 0; mt < MT; ++mt) acc[mt][jt] = (f32x4){bv, bv, bv, bv};
  }
  for (int kt = 0; kt < 8; ++kt) {
    const int k0 = kt * 64;
    #pragma unroll
    for (int i = 0; i < 8; ++i) {             // wave's own W1 stripe: 8 KB
      const __hip_bfloat16* gp = W1T + (size_t)(colw + i*8 + csub) * 512 + k0 + jsrc*8;
      gl2lds16(gp, (char*)Wt + w*8192 + i*1024);
    }
    #pragma unroll
    for (int t = 0; t < 2; ++t) {             // A-tile: gathered per-lane sources
      int i = w + 4*t;
      if (i < MT*2) {
        const __hip_bfloat16* gp =
            (k0 < 256 ? ar0[t] + k0 : ar1[t] + (k0 - 256)) + jsrc*8;
        gl2lds16(gp, (char*)At + i*1024);
      }
    }
    __syncthreads();
    #pragma unroll
    for (int ks = 0; ks < 2; ++ks) {
      const int sw = ks ? swz1 : swz0;
      short8 af[MT], bf[4];
      #pragma unroll
      for (int mt = 0; mt < MT; ++mt)
        af[mt] = *(const short8*)((const char*)At + (mt*16 + m16)*128 + sw);
      #pragma unroll
      for (int jt = 0; jt < 4; ++jt)
        bf[jt] = *(const short8*)((const char*)Wt + (colw + jt*16 + m16)*128 + sw);
      #pragma unroll
      for (int mt = 0; mt < MT; ++mt)
        #pragma unroll
        for (int jt = 0; jt < 4; ++jt)
          acc[mt][jt] = __builtin_amdgcn_mfma_f32_16x16x32_bf16(af[mt], bf[jt],
                                                                acc[mt][jt], 0, 0, 0);
    }
    __syncthreads();
  }
  // ELU(h1) -> LDS (C-layout: col=lane&15, row=quad*4+reg)
  #pragma unroll
  for (int mt = 0; mt < MT; ++mt)
    #pragma unroll
    for (int jt = 0; jt < 4; ++jt)
      #pragma unroll
      for (int r = 0; r < 4; ++r)
        h1s[mt*16 + quad*4 + r][colw + jt*16 + m16] =
            __float2bfloat16(eluf(acc[mt][jt][r]));
  __syncthreads();

  // ---- layer 2: ROWSx256 @ 256x256 ----
  f32x4 acc2[MT][4];
  #pragma unroll
  for (int jt = 0; jt < 4; ++jt) {
    float bv = b2[colw + jt*16 + m16];
    #pragma unroll
    for (int mt = 0; mt < MT; ++mt) acc2[mt][jt] = (f32x4){bv, bv, bv, bv};
  }
  for (int kt = 0; kt < 4; ++kt) {
    const int k0 = kt * 64;
    #pragma unroll
    for (int i = 0; i < 8; ++i) {
      const __hip_bfloat16* gp = W2T + (size_t)(colw + i*8 + csub) * 256 + k0 + jsrc*8;
      gl2lds16(gp, (char*)Wt + w*8192 + i*1024);
    }
    __syncthreads();
    #pragma unroll
    for (int ks = 0; ks < 2; ++ks) {
      const int sw = ks ? swz1 : swz0;
      short8 af[MT], bf[4];
      #pragma unroll
      for (int mt = 0; mt < MT; ++mt)
        af[mt] = *(const short8*)((const char*)h1s +
                     (size_t)(mt*16 + m16)*528 + (k0 + ks*32 + ko)*2);
      #pragma unroll
      for (int jt = 0; jt < 4; ++jt)
        bf[jt] = *(const short8*)((const char*)Wt + (colw + jt*16 + m16)*128 + sw);
      #pragma unroll
      for (int mt = 0; mt < MT; ++mt)
        #pragma unroll
        for (int jt = 0; jt < 4; ++jt)
          acc2[mt][jt] = __builtin_amdgcn_mfma_f32_16x16x32_bf16(af[mt], bf[jt],
                                                                 acc2[mt][jt], 0, 0, 0);
    }
    __syncthreads();
  }
  // ELU(h2) -> LDS (h1 reads all done at last barrier)
  #pragma unroll
  for (int mt = 0; mt < MT; ++mt)
    #pragma unroll
    for (int jt = 0; jt < 4; ++jt)
      #pragma unroll
      for (int r = 0; r < 4; ++r)
        h1s[mt*16 + quad*4 + r][colw + jt*16 + m16] =
            __float2bfloat16(eluf(acc2[mt][jt][r]));
  __syncthreads();

  // ---- fused BN stats ----
  {
    float s = 0.f, q = 0.f;
    #pragma unroll 8
    for (int r = 0; r < ROWS; ++r) {
      float v = __bfloat162float(h1s[r][tid]);
      s += v; q += v * v;
    }
    atomicAdd(&stats[tid], s);
    atomicAdd(&stats[256 + tid], q);
  }
  // ---- vectorized bf16 store ----
  #pragma unroll
  for (int i = 0; i < ROWS/8; ++i) {
    int u = i*256 + tid;
    int r = u >> 5, c = (u & 31) * 8;
    *reinterpret_cast<uint4*>(outp + (size_t)(row0 + r)*HH + c) =
        *reinterpret_cast<const uint4*>(&h1s[r][c]);
  }
}

// ---- BN-fused edge->node aggregation (finalize math inlined) ----
__global__ __launch_bounds__(256) void k_agg(const __hip_bfloat16* __restrict__ e2,
                                             const float* __restrict__ st,
                                             const float* __restrict__ gam,
                                             const float* __restrict__ bet,
                                             __hip_bfloat16* __restrict__ nodes) {
  int tid = threadIdx.x;
  int c2 = (tid & 127) * 2, half = tid >> 7;
  int bn = blockIdx.x; int b = bn >> 6; int n = bn & 63;
  const __hip_bfloat16* base = e2 + (size_t)b * EE * HH;
  float s0 = 0.f, s1 = 0.f;
  if (half == 0) {
    for (int j = 0; j < 63; ++j) {
      __hip_bfloat162 v = *reinterpret_cast<const __hip_bfloat162*>(
          base + (size_t)(n*63 + j)*HH + c2);
      s0 += __bfloat162float(v.x); s1 += __bfloat162float(v.y);
    }
  } else {
    for (int i = 0; i < NN; ++i) {
      if (i == n) continue;
      int e = i*63 + n - (n > i ? 1 : 0);
      __hip_bfloat162 v = *reinterpret_cast<const __hip_bfloat162*>(
          base + (size_t)e*HH + c2);
      s0 += __bfloat162float(v.x); s1 += __bfloat162float(v.y);
    }
  }
  const float inv = 1.f / (float)EROWS;
  float m0 = st[c2] * inv,     m1 = st[c2+1] * inv;
  float v0 = fmaxf(st[256+c2]*inv - m0*m0, 0.f), v1 = fmaxf(st[256+c2+1]*inv - m1*m1, 0.f);
  float a0 = gam[c2] * rsqrtf(v0 + 1e-5f),  a1 = gam[c2+1] * rsqrtf(v1 + 1e-5f);
  float k0 = bet[c2] - m0*a0,               k1 = bet[c2+1] - m1*a1;
  __hip_bfloat162 o;
  o.x = __float2bfloat16(a0 * s0 * (1.f/63.f) + k0);
  o.y = __float2bfloat16(a1 * s1 * (1.f/63.f) + k1);
  *reinterpret_cast<__hip_bfloat162*>(nodes + (size_t)bn*512 + half*256 + c2) = o;
}

// ---- build fin = [xb, BN(m2)] (finalize math inlined) ----
__global__ __launch_bounds__(256) void k_bnm(const __hip_bfloat16* __restrict__ xb,
                                             const __hip_bfloat16* __restrict__ m2,
                                             const float* __restrict__ st,
                                             const float* __restrict__ gam,
                                             const float* __restrict__ bet,
                                             __hip_bfloat16* __restrict__ fin) {
  int row = blockIdx.x, tid = threadIdx.x;
  fin[(size_t)row*512 + tid] = xb[(size_t)row*256 + tid];
  const float inv = 1.f / (float)NROWS;
  float mean = st[tid] * inv;
  float var  = fmaxf(st[256 + tid] * inv - mean*mean, 0.f);
  float am = gam[tid] * rsqrtf(var + 1e-5f);
  float cm = bet[tid] - mean * am;
  float v = __bfloat162float(m2[(size_t)row*256 + tid]);
  fin[(size_t)row*512 + 256 + tid] = __float2bfloat16(am * v + cm);
}

// ---- head via MFMA (16 blocks; round-4 structure) ----
__global__ __launch_bounds__(256) void k_head_mfma(
    const __hip_bfloat16* __restrict__ fin,   // 1024 x 512
    const __hip_bfloat16* __restrict__ WfT,   // 256 x 512
    const float* __restrict__ bfv,
    const __hip_bfloat16* __restrict__ WpT,   // 64 x 256 (zero-padded)
    const float* __restrict__ bp,
    const float* __restrict__ centers,
    float* __restrict__ out) {
  __shared__ alignas(16) __hip_bfloat16 hs[64][264];
  __shared__ float rl[64][64];
  const int tid = threadIdx.x;
  const int w = tid >> 6, lane = tid & 63;
  const int m16 = lane & 15, quad = lane >> 4;
  const int ko = quad * 8;
  const int row0 = blockIdx.x * 64;
  const int colw = w * 64;

  f32x4 acc[4][4];
  #pragma unroll
  for (int jt = 0; jt < 4; ++jt) {
    float bv = bfv[colw + jt*16 + m16];
    #pragma unroll
    for (int mt = 0; mt < 4; ++mt) acc[mt][jt] = (f32x4){bv, bv, bv, bv};
  }
  #pragma unroll
  for (int ks = 0; ks < 16; ++ks) {
    short8 af[4], bf[4];
    #pragma unroll
    for (int mt = 0; mt < 4; ++mt)
      af[mt] = *reinterpret_cast<const short8*>(
          fin + (size_t)(row0 + mt*16 + m16)*512 + ks*32 + ko);
    #pragma unroll
    for (int jt = 0; jt < 4; ++jt)
      bf[jt] = *reinterpret_cast<const short8*>(
          WfT + (size_t)(colw + jt*16 + m16)*512 + ks*32 + ko);
    #pragma unroll
    for (int mt = 0; mt < 4; ++mt)
      #pragma unroll
      for (int jt = 0; jt < 4; ++jt)
        acc[mt][jt] = __builtin_amdgcn_mfma_f32_16x16x32_bf16(af[mt], bf[jt],
                                                              acc[mt][jt], 0, 0, 0);
  }
  #pragma unroll
  for (int mt = 0; mt < 4; ++mt)
    #pragma unroll
    for (int jt = 0; jt < 4; ++jt)
      #pragma unroll
      for (int r = 0; r < 4; ++r)
        hs[mt*16 + quad*4 + r][colw + jt*16 + m16] =
            __float2bfloat16(acc[mt][jt][r]);
  __syncthreads();

  if (w == 0) {
    f32x4 acc2[4][4];
    #pragma unroll
    for (int jt = 0; jt < 4; ++jt) {
      int c = jt*16 + m16;
      float bv = (c < 60) ? bp[c] : 0.f;
      #pragma unroll
      for (int mt = 0; mt < 4; ++mt) acc2[mt][jt] = (f32x4){bv, bv, bv, bv};
    }
    #pragma unroll
    for (int ks = 0; ks < 8; ++ks) {
      short8 af[4], bf[4];
      #pragma unroll
      for (int mt = 0; mt < 4; ++mt)
        af[mt] = *reinterpret_cast<const short8*>(&hs[mt*16 + m16][ks*32 + ko]);
      #pragma unroll
      for (int jt = 0; jt < 4; ++jt)
        bf[jt] = *reinterpret_cast<const short8*>(
            WpT + (size_t)(jt*16 + m16)*256 + ks*32 + ko);
      #pragma unroll
      for (int mt = 0; mt < 4; ++mt)
        #pragma unroll
        for (int jt = 0; jt < 4; ++jt)
          acc2[mt][jt] = __builtin_amdgcn_mfma_f32_16x16x32_bf16(af[mt], bf[jt],
                                                                 acc2[mt][jt], 0, 0, 0);
    }
    #pragma unroll
    for (int mt = 0; mt < 4; ++mt)
      #pragma unroll
      for (int jt = 0; jt < 4; ++jt) {
        int c = jt*16 + m16;
        #pragma unroll
        for (int r = 0; r < 4; ++r) {
          int lr = mt*16 + quad*4 + r;
          rl[lr][c] = acc2[mt][jt][r];
          if (c < 60) out[(size_t)(row0 + lr)*60 + c] = acc2[mt][jt][r];
        }
      }
  }
  __syncthreads();

  if (tid < 128) {
    int lr = tid >> 1, xy = tid & 1;
    int grow = row0 + lr;
    float run = centers[(size_t)(grow*PREVN + 5)*2 + xy];
    #pragma unroll
    for (int p = 0; p < PREDN; ++p) {
      run += rl[lr][2*p + xy];
      out[61440 + (size_t)grow*60 + 2*p + xy] = run;
    }
  }
}

extern "C" void kernel_launch(void* const* d_in, const int* in_sizes, int n_in,
                              void* d_out, int out_size, void* d_ws, size_t ws_size,
                              hipStream_t stream) {
  const float* centers = (const float*)d_in[0];
  float* ws = (float*)d_ws;
  __hip_bfloat16* wb = (__hip_bfloat16*)(ws + F32_END);

  PrepArgs pa;
  pa.centers = centers;
  pa.W_traj = (const float*)d_in[3];  pa.b_traj = (const float*)d_in[4];
  pa.n2e_W1 = (const float*)d_in[5];  pa.n2e_W2 = (const float*)d_in[7];
  pa.e2n_W1 = (const float*)d_in[11]; pa.e2n_W2 = (const float*)d_in[13];
  pa.W_fuse = (const float*)d_in[17]; pa.W_pred = (const float*)d_in[19];
  pa.stats = ws;
  pa.xb = wb + BO_XB; pa.w1te = wb + BO_W1TE; pa.w2te = wb + BO_W2TE;
  pa.w1tn = wb + BO_W1TN; pa.w2tn = wb + BO_W2TN; pa.wft = wb + BO_WFT;
  pa.wpt = wb + BO_WPT;

  const float* n2e_b1 = (const float*)d_in[6];
  const float* n2e_b2 = (const float*)d_in[8];
  const float* n2e_g  = (const float*)d_in[9];
  const float* n2e_be = (const float*)d_in[10];
  const float* e2n_b1 = (const float*)d_in[12];
  const float* e2n_b2 = (const float*)d_in[14];
  const float* e2n_g  = (const float*)d_in[15];
  const float* e2n_be = (const float*)d_in[16];
  const float* b_fuse = (const float*)d_in[18];
  const float* b_pred = (const float*)d_in[20];

  k_prep<<<1224, 256, 0, stream>>>(pa);
  k_mlp3<0><<<EROWS/64, 256, 0, stream>>>(wb + BO_XB, wb + BO_W1TE, n2e_b1,
                                          wb + BO_W2TE, n2e_b2,
                                          wb + BO_E2, ws + OFF_STATS_E);
  k_agg<<<NROWS, 256, 0, stream>>>(wb + BO_E2, ws + OFF_STATS_E, n2e_g, n2e_be,
                                   wb + BO_NODES);
  k_mlp3<1><<<NROWS/16, 256, 0, stream>>>(wb + BO_NODES, wb + BO_W1TN, e2n_b1,
                                          wb + BO_W2TN, e2n_b2,
                                          wb + BO_M2, ws + OFF_STATS_M);
  k_bnm<<<NROWS, 256, 0, stream>>>(wb + BO_XB, wb + BO_M2, ws + OFF_STATS_M,
                                   e2n_g, e2n_be, wb + BO_NODES);
  k_head_mfma<<<NROWS/64, 256, 0, stream>>>(wb + BO_NODES, wb + BO_WFT, b_fuse,
                                            wb + BO_WPT, b_pred, centers,
                                            (float*)d_out);
}